// Round 5
// baseline (965.411 us; speedup 1.0000x reference)
//
#include <hip/hip_runtime.h>

// GATCL: 2-head GAT (N=8192, D=256) + feature conv (K=129) + GAT(D=128) + 2 MLPs + pair dots.
// R5: atomic-free aggregation. agg_head: 512-thr blocks, full-j, plain stores (1 writer/elem).
// agg_conv: 512-thr blocks, j-split 2 into plain-store partials merged in k_mlp.
// Pipelined staging, XOR-swizzled LDS (0 conflicts), fp16 MFMA 16x16x32.

typedef _Float16 f16;
typedef _Float16 f16x8 __attribute__((ext_vector_type(8)));
typedef float f32x4 __attribute__((ext_vector_type(4)));

#define DEV __device__ __forceinline__
#define L2E 1.4426950408889634f
#define NN 8192
#define IND 768
#define D1 256
#define DT 512
#define D2 128
#define KC 129
#define EPAIRS 100000

#if __has_builtin(__builtin_amdgcn_exp2f)
#define EXP2(x) __builtin_amdgcn_exp2f(x)
#else
#define EXP2(x) exp2f(x)
#endif

DEV float eluf(float x){ return x > 0.f ? x : EXP2(x*L2E) - 1.f; }

// ---------------- P: fused prep = pack(adj->bits) + cast(x->fp16) + Wt transpose ----------------
__global__ __launch_bounds__(256) void k_prep(
    const int4* __restrict__ adj4, unsigned* __restrict__ maskw,
    const float* __restrict__ x, f16* __restrict__ x16,
    const float* __restrict__ W, f16* __restrict__ Wt){
  int b = blockIdx.x, t = threadIdx.x;
  if (b < 65536){
    int idx = b*256 + t;
    int4 v = adj4[idx];
    unsigned n = (unsigned)(v.x > 0) | ((unsigned)(v.y > 0) << 1)
               | ((unsigned)(v.z > 0) << 2) | ((unsigned)(v.w > 0) << 3);
    n |= __shfl_xor(n, 1) << 4;
    n |= __shfl_xor(n, 2) << 8;
    n |= __shfl_xor(n, 4) << 16;
    if ((t & 7) == 0) maskw[idx >> 3] = n;
  } else if (b < 65536 + 6144){
    int i = ((b - 65536)*256 + t)*4;
    float4 v = *(const float4*)(x + i);
    union { f16 h[4]; uint2 u; } p;
    p.h[0]=(f16)v.x; p.h[1]=(f16)v.y; p.h[2]=(f16)v.z; p.h[3]=(f16)v.w;
    *(uint2*)(x16 + i) = p.u;
  } else {
    int np = b - 71680; int h = np >> 8, d = np & 255;
    for (int k = t; k < IND; k += 256)
      Wt[(size_t)np*IND + k] = (f16)W[((size_t)h*IND + k)*D1 + d];
  }
}

// ---------------- G1: h = x @ W' (8192x512), swizzled LDS, prefetch, coalesced hT store ----------------
__global__ __launch_bounds__(256) void k_gemm_h(
    const f16* __restrict__ x16, const f16* __restrict__ Wt,
    const float* __restrict__ head_a,
    f16* __restrict__ hT, float* __restrict__ wh1, float* __restrict__ wh2){
  __shared__ f16 SM[(64 + 128)*64];
  f16* As = SM;
  f16* Bs = SM + 64*64;
  int m0 = blockIdx.x*64, n0 = blockIdx.y*128;
  int t = threadIdx.x, lane = t & 63, w = t >> 6;
  int wi = w >> 1, wd = w & 1;
  int rm = lane & 15, q4 = lane >> 4;
  int drb = t >> 3, gofs = (t & 7)*8;
  int sg8 = (((t & 7) ^ ((t >> 3) & 7))*8);
  f32x4 acc[2][4] = {};
  uint4 preA[2], preB[4];
#pragma unroll
  for (int p = 0; p < 2; p++)
    preA[p] = *(const uint4*)&x16[(size_t)(m0 + p*32 + drb)*IND + gofs];
#pragma unroll
  for (int p = 0; p < 4; p++)
    preB[p] = *(const uint4*)&Wt[(size_t)(n0 + p*32 + drb)*IND + gofs];
  for (int k0 = 0; k0 < IND; k0 += 64){
    __syncthreads();
#pragma unroll
    for (int p = 0; p < 2; p++) *(uint4*)&As[(p*32 + drb)*64 + sg8] = preA[p];
#pragma unroll
    for (int p = 0; p < 4; p++) *(uint4*)&Bs[(p*32 + drb)*64 + sg8] = preB[p];
    __syncthreads();
    if (k0 + 64 < IND){
#pragma unroll
      for (int p = 0; p < 2; p++)
        preA[p] = *(const uint4*)&x16[(size_t)(m0 + p*32 + drb)*IND + k0 + 64 + gofs];
#pragma unroll
      for (int p = 0; p < 4; p++)
        preB[p] = *(const uint4*)&Wt[(size_t)(n0 + p*32 + drb)*IND + k0 + 64 + gofs];
    }
#pragma unroll
    for (int ks = 0; ks < 2; ks++){
      int gl = ks*4 + q4;
      int r0 = wi*32 + rm, r1 = wi*32 + 16 + rm;
      f16x8 a0 = *(const f16x8*)&As[r0*64 + ((gl ^ (r0 & 7))*8)];
      f16x8 a1 = *(const f16x8*)&As[r1*64 + ((gl ^ (r1 & 7))*8)];
#pragma unroll
      for (int fn = 0; fn < 4; fn++){
        int rb = wd*64 + fn*16 + rm;
        f16x8 b = *(const f16x8*)&Bs[rb*64 + ((gl ^ (rb & 7))*8)];
        acc[0][fn] = __builtin_amdgcn_mfma_f32_16x16x32_f16(a0, b, acc[0][fn], 0, 0, 0);
        acc[1][fn] = __builtin_amdgcn_mfma_f32_16x16x32_f16(a1, b, acc[1][fn], 0, 0, 0);
      }
    }
  }
  int quad = lane >> 4, cl = lane & 15;
  int head = n0 >> 8;
  // transpose C into LDS then coalesced hT store (full 128x64 tile)
  f16* T = SM;
  __syncthreads();
#pragma unroll
  for (int fi = 0; fi < 2; fi++)
#pragma unroll
    for (int fn = 0; fn < 4; fn++){
      int d = wd*64 + fn*16 + cl;
      int i = wi*32 + fi*16 + quad*4;
      union { f16 h[4]; uint2 u; } pk;
#pragma unroll
      for (int reg = 0; reg < 4; reg++) pk.h[reg] = (f16)acc[fi][fn][reg];
      *(uint2*)&T[d*72 + i] = pk.u;
    }
  __syncthreads();
  { int row = t >> 1, half = t & 1;
    const f16* src = &T[row*72 + half*32];
    f16* dst = &hT[(size_t)(n0 + row)*NN + m0 + half*32];
#pragma unroll
    for (int q = 0; q < 4; q++)
      *(uint4*)&dst[q*8] = *(const uint4*)&src[q*8];
  }
  float a1v[4], a2v[4];
#pragma unroll
  for (int fn = 0; fn < 4; fn++){
    int d = (n0 & 255) + wd*64 + fn*16 + cl;
    a1v[fn] = head_a[head*DT + d];
    a2v[fn] = head_a[head*DT + D1 + d];
  }
  float p1[2][4], p2[2][4];
#pragma unroll
  for (int fi = 0; fi < 2; fi++)
#pragma unroll
    for (int reg = 0; reg < 4; reg++){
      float s1 = 0.f, s2 = 0.f;
#pragma unroll
      for (int fn = 0; fn < 4; fn++){ s1 += acc[fi][fn][reg]*a1v[fn]; s2 += acc[fi][fn][reg]*a2v[fn]; }
      p1[fi][reg] = s1; p2[fi][reg] = s2;
    }
#pragma unroll
  for (int o = 1; o < 16; o <<= 1){
#pragma unroll
    for (int fi = 0; fi < 2; fi++)
#pragma unroll
      for (int reg = 0; reg < 4; reg++){
        p1[fi][reg] += __shfl_xor(p1[fi][reg], o);
        p2[fi][reg] += __shfl_xor(p2[fi][reg], o);
      }
  }
  if (cl == 0){
#pragma unroll
    for (int fi = 0; fi < 2; fi++)
#pragma unroll
      for (int reg = 0; reg < 4; reg++){
        int mg = m0 + wi*32 + fi*16 + quad*4 + reg;
        atomicAdd(&wh1[head*NN + mg], p1[fi][reg]);
        atomicAdd(&wh2[head*NN + mg], p2[fi][reg]);
      }
  }
}

// ---------------- R: rowterms = colterms + per-head global max of wh2 ----------------
__global__ __launch_bounds__(256) void k_rowterms(const float* __restrict__ wh2,
    float* __restrict__ c1, float* __restrict__ c2, unsigned* __restrict__ gmax){
  int i = blockIdx.x*256 + threadIdx.x;
  float v = wh2[i];
  c1[i] = v*L2E; c2[i] = 0.2f*v*L2E;
  float m = v;
#pragma unroll
  for (int o = 32; o > 0; o >>= 1) m = fmaxf(m, __shfl_xor(m, o));
  if ((threadIdx.x & 63) == 0){
    unsigned bbits = __float_as_uint(m);
    unsigned enc = (bbits & 0x80000000u) ? ~bbits : (bbits | 0x80000000u);
    atomicMax(gmax + (i >> 13), enc);
  }
}

// ---------------- A1: head GAT agg. 512 thr, i-tile 64, full j, plain stores ----------------
__global__ __launch_bounds__(512, 2) void k_agg_head(
    const f16* __restrict__ hT, const unsigned* __restrict__ maskw,
    const float* __restrict__ wh1, const float* __restrict__ c1,
    const float* __restrict__ c2, const unsigned* __restrict__ gmaxp,
    float* __restrict__ num, float* __restrict__ den){
  __shared__ f16 Hs[256*64];   // 32 KB
  __shared__ f16 Ws[64*64];    // 8 KB
  int head = blockIdx.y;
  int i0 = blockIdx.x*64;
  const f16* hTh = hT + (size_t)head*D1*NN;
  int t = threadIdx.x, lane = t & 63, w = t >> 6;
  int rm = lane & 15, q4 = lane >> 4;
  int si = t >> 3, sg = t & 7, sjq = sg*8;
  unsigned e = gmaxp[head];
  float gmax = __uint_as_float((e & 0x80000000u) ? (e ^ 0x80000000u) : ~e);
  float u = wh1[head*NN + i0 + si];
  float sm = u + gmax;
  float M = (sm > 0.f ? sm : 0.2f*sm)*L2E;   // leaky(wh1+gmax) in log2 units
  float ra = u*L2E - M, rb = 0.2f*u*L2E - M;
  const float* c1h = c1 + head*NN;
  const float* c2h = c2 + head*NN;
  const unsigned* mrowp = maskw + (size_t)(i0 + si)*(NN/32);
  float rden = 0.f;
  f32x4 acc[4][2] = {};
  int r_[4], g_[4];
  uint4 pre[4];
#pragma unroll
  for (int p = 0; p < 4; p++){
    int idx = p*512 + t; r_[p] = idx >> 3; g_[p] = idx & 7;
    pre[p] = *(const uint4*)&hTh[(size_t)r_[p]*NN + g_[p]*8];
  }
  for (int j0 = 0; j0 < NN; j0 += 64){
    __syncthreads();
#pragma unroll
    for (int p = 0; p < 4; p++)
      *(uint4*)&Hs[r_[p]*64 + ((g_[p] ^ (r_[p] & 7))*8)] = pre[p];
    unsigned mb = mrowp[(unsigned)(j0 + sjq) >> 5] >> (sjq & 31);
    float ca[8], cb[8];
    { float4 va0 = *(const float4*)&c1h[j0 + sjq];
      float4 va1 = *(const float4*)&c1h[j0 + sjq + 4];
      float4 vb0 = *(const float4*)&c2h[j0 + sjq];
      float4 vb1 = *(const float4*)&c2h[j0 + sjq + 4];
      ca[0]=va0.x; ca[1]=va0.y; ca[2]=va0.z; ca[3]=va0.w;
      ca[4]=va1.x; ca[5]=va1.y; ca[6]=va1.z; ca[7]=va1.w;
      cb[0]=vb0.x; cb[1]=vb0.y; cb[2]=vb0.z; cb[3]=vb0.w;
      cb[4]=vb1.x; cb[5]=vb1.y; cb[6]=vb1.z; cb[7]=vb1.w; }
    f16x8 wloc;
    float dsum = 0.f;
#pragma unroll
    for (int q = 0; q < 8; q++){
      float s1 = ra + ca[q], s2 = rb + cb[q];
      float wv = EXP2(fmaxf(s1, s2));          // exp(leaky(s)-m) <= 1
      wv = ((mb >> q) & 1u) ? wv : 0.f;
      dsum += wv;
      wloc[q] = (f16)wv;
    }
    *(f16x8*)&Ws[si*64 + ((sg ^ (si & 7))*8)] = wloc;
    rden += dsum;
    __syncthreads();
    if (j0 + 64 < NN){
#pragma unroll
      for (int p = 0; p < 4; p++)
        pre[p] = *(const uint4*)&hTh[(size_t)r_[p]*NN + j0 + 64 + g_[p]*8];
    }
#pragma unroll
    for (int ks = 0; ks < 2; ks++){
      int gl = ks*4 + q4;
      f16x8 a[4], b[2];
#pragma unroll
      for (int mi = 0; mi < 4; mi++){
        int row = mi*16 + rm;
        a[mi] = *(const f16x8*)&Ws[row*64 + ((gl ^ (row & 7))*8)];
      }
#pragma unroll
      for (int fn = 0; fn < 2; fn++){
        int row = w*32 + fn*16 + rm;
        b[fn] = *(const f16x8*)&Hs[row*64 + ((gl ^ (row & 7))*8)];
      }
#pragma unroll
      for (int mi = 0; mi < 4; mi++)
#pragma unroll
        for (int fn = 0; fn < 2; fn++)
          acc[mi][fn] = __builtin_amdgcn_mfma_f32_16x16x32_f16(a[mi], b[fn], acc[mi][fn], 0, 0, 0);
    }
  }
  rden += __shfl_xor(rden, 1);
  rden += __shfl_xor(rden, 2);
  rden += __shfl_xor(rden, 4);
  if (sg == 0) den[head*NN + i0 + si] = rden;
  int quad = lane >> 4, cl = lane & 15;
#pragma unroll
  for (int mi = 0; mi < 4; mi++)
#pragma unroll
    for (int fn = 0; fn < 2; fn++){
      int rr = i0 + mi*16 + quad*4;
      int dc = w*32 + fn*16 + cl;
#pragma unroll
      for (int reg = 0; reg < 4; reg++)
        num[((size_t)head*NN + rr + reg)*D1 + dc] = acc[mi][fn][reg];
    }
}

// ---------------- E1: merge heads -> z -> conv -> gT(fp16) + wc1L/wc2L ----------------
__global__ __launch_bounds__(256) void k_merge_conv(
    const float* __restrict__ num, const float* __restrict__ den,
    const float* __restrict__ head_b, const float* __restrict__ conv_w,
    const float* __restrict__ conv_cb, const float* __restrict__ conv_a,
    f16* __restrict__ gT, float* __restrict__ wc1L, float* __restrict__ wc2L){
  __shared__ float zrow[2][256];
  __shared__ float cw[KC];
  __shared__ float ca[256];
  __shared__ float red[2][2];
  __shared__ float red2[2][2][2];
  int t = threadIdx.x, g = t >> 7, c = t & 127;
  int r = blockIdx.x*2 + g;
  if (t < KC) cw[t] = conv_w[t];
  ca[t] = conv_a[t];
  float zv0 = 0.f, zv1 = 0.f;
#pragma unroll
  for (int h = 0; h < 2; h++){
    const float* nr = num + ((size_t)h*NN + r)*D1;
    float inv = 1.f / den[h*NN + r];
    float e0 = eluf(nr[c]*inv);
    float e1 = eluf(nr[c + 128]*inv);
    float ss = e0*e0 + e1*e1;
#pragma unroll
    for (int o = 32; o > 0; o >>= 1) ss += __shfl_xor(ss, o);
    if ((t & 63) == 0) red[g][(t >> 6) & 1] = ss;
    __syncthreads();
    float invn = 1.f / fmaxf(sqrtf(red[g][0] + red[g][1]), 1e-12f);
    zv0 += e0*invn + head_b[h*D1 + c];
    zv1 += e1*invn + head_b[h*D1 + 128 + c];
    __syncthreads();
  }
  zrow[g][c]       = eluf(0.5f*zv0);
  zrow[g][c + 128] = eluf(0.5f*zv1);
  __syncthreads();
  float s = conv_cb[0];
  for (int k = 0; k < KC; k++) s += zrow[g][c + k]*cw[k];
  gT[(size_t)c*NN + r] = (f16)s;
  float p1 = s*ca[c], p2 = s*ca[128 + c];
#pragma unroll
  for (int o = 32; o > 0; o >>= 1){ p1 += __shfl_xor(p1, o); p2 += __shfl_xor(p2, o); }
  if ((t & 63) == 0){ red2[g][(t >> 6) & 1][0] = p1; red2[g][(t >> 6) & 1][1] = p2; }
  __syncthreads();
  if ((t & 127) == 0){
    wc1L[r] = (red2[g][0][0] + red2[g][1][0])*L2E;
    wc2L[r] = (red2[g][0][1] + red2[g][1][1])*L2E;
  }
}

// ---------------- A2: conv GAT agg. 512 thr, i-tile 64, j-split 2 into partials ----------------
__global__ __launch_bounds__(512, 2) void k_agg_conv(
    const f16* __restrict__ gT, const unsigned* __restrict__ maskw,
    const float* __restrict__ wc1L, const float* __restrict__ wc2L,
    float* __restrict__ numcp, float* __restrict__ dencp){
  __shared__ f16 Hs[128*64];   // 16 KB
  __shared__ f16 Ws[64*64];    // 8 KB
  int i0 = blockIdx.x*64;
  int jsp = blockIdx.y, jbase = jsp*4096;
  int t = threadIdx.x, lane = t & 63, w = t >> 6;
  int rm = lane & 15, q4 = lane >> 4;
  int si = t >> 3, sg = t & 7, sjq = sg*8;
  float ra = wc1L[i0 + si];
  const unsigned* mrowp = maskw + (size_t)(i0 + si)*(NN/32);
  float rden = 0.f;
  f32x4 acc[4] = {};
  int r_[2], g_[2];
  uint4 pre[2];
#pragma unroll
  for (int p = 0; p < 2; p++){
    int idx = p*512 + t; r_[p] = idx >> 3; g_[p] = idx & 7;
    pre[p] = *(const uint4*)&gT[(size_t)r_[p]*NN + jbase + g_[p]*8];
  }
  for (int j0 = 0; j0 < 4096; j0 += 64){
    int jg = jbase + j0;
    __syncthreads();
#pragma unroll
    for (int p = 0; p < 2; p++)
      *(uint4*)&Hs[r_[p]*64 + ((g_[p] ^ (r_[p] & 7))*8)] = pre[p];
    unsigned mb = mrowp[(unsigned)(jg + sjq) >> 5] >> (sjq & 31);
    float cc[8];
    { float4 v0 = *(const float4*)&wc2L[jg + sjq];
      float4 v1 = *(const float4*)&wc2L[jg + sjq + 4];
      cc[0]=v0.x; cc[1]=v0.y; cc[2]=v0.z; cc[3]=v0.w;
      cc[4]=v1.x; cc[5]=v1.y; cc[6]=v1.z; cc[7]=v1.w; }
    f16x8 wloc;
    float dsum = 0.f;
#pragma unroll
    for (int q = 0; q < 8; q++){
      float sL = ra + cc[q];                   // s*log2e
      float t2 = EXP2(sL);                     // e^s
      float wv = sL > 0.f ? t2 : EXP2((t2 - 1.f)*L2E);  // exp(elu(s))
      wv = ((mb >> q) & 1u) ? wv : 0.f;
      dsum += wv;
      wloc[q] = (f16)wv;
    }
    *(f16x8*)&Ws[si*64 + ((sg ^ (si & 7))*8)] = wloc;
    rden += dsum;
    __syncthreads();
    if (j0 + 64 < 4096){
#pragma unroll
      for (int p = 0; p < 2; p++)
        pre[p] = *(const uint4*)&gT[(size_t)r_[p]*NN + jg + 64 + g_[p]*8];
    }
#pragma unroll
    for (int ks = 0; ks < 2; ks++){
      int gl = ks*4 + q4;
      f16x8 a[4], b;
#pragma unroll
      for (int mi = 0; mi < 4; mi++){
        int row = mi*16 + rm;
        a[mi] = *(const f16x8*)&Ws[row*64 + ((gl ^ (row & 7))*8)];
      }
      { int row = w*16 + rm;
        b = *(const f16x8*)&Hs[row*64 + ((gl ^ (row & 7))*8)]; }
#pragma unroll
      for (int mi = 0; mi < 4; mi++)
        acc[mi] = __builtin_amdgcn_mfma_f32_16x16x32_f16(a[mi], b, acc[mi], 0, 0, 0);
    }
  }
  rden += __shfl_xor(rden, 1);
  rden += __shfl_xor(rden, 2);
  rden += __shfl_xor(rden, 4);
  if (sg == 0) dencp[(size_t)jsp*NN + i0 + si] = rden;
  int quad = lane >> 4, cl = lane & 15;
  float* numo = numcp + (size_t)jsp*NN*D2;
#pragma unroll
  for (int mi = 0; mi < 4; mi++){
    int rr = i0 + mi*16 + quad*4;
    int dc = w*16 + cl;
#pragma unroll
    for (int reg = 0; reg < 4; reg++)
      numo[(size_t)(rr + reg)*D2 + dc] = acc[mi][reg];
  }
}

// ---------------- E3: fused embed (merge 2 conv partials) + two MLPs ----------------
__global__ __launch_bounds__(256) void k_mlp(
    const float* __restrict__ numcp, const float* __restrict__ dencp,
    const float* __restrict__ conv_b,
    const float* __restrict__ fw1, const float* __restrict__ fb1,
    const float* __restrict__ fw2, const float* __restrict__ fb2,
    const float* __restrict__ gw1, const float* __restrict__ gb1,
    const float* __restrict__ gw2, const float* __restrict__ gb2,
    float* __restrict__ tf, float* __restrict__ tg){
  const float* w1 = blockIdx.y ? gw1 : fw1;
  const float* b1 = blockIdx.y ? gb1 : fb1;
  const float* w2 = blockIdx.y ? gw2 : fw2;
  const float* b2 = blockIdx.y ? gb2 : fb2;
  float* out = blockIdx.y ? tg : tf;
  int t = threadIdx.x;
  int c = t & 127, kh = t >> 7;
  int o = t & 63, kh2 = t >> 6;
  int r0 = blockIdx.x*32;
  __shared__ float es[32][132];
  { int row = t >> 3, c0 = (t & 7)*16;
    int rg = r0 + row;
    float inv = 1.f / (dencp[rg] + dencp[NN + rg]);
    float ev[16]; float ss = 0.f;
#pragma unroll
    for (int k = 0; k < 4; k++){
      float4 v0 = *(const float4*)&numcp[(size_t)rg*D2 + c0 + 4*k];
      float4 v1 = *(const float4*)&numcp[(size_t)(NN + rg)*D2 + c0 + 4*k];
      float e0 = eluf((v0.x + v1.x)*inv), e1 = eluf((v0.y + v1.y)*inv);
      float e2 = eluf((v0.z + v1.z)*inv), e3 = eluf((v0.w + v1.w)*inv);
      ev[4*k]=e0; ev[4*k+1]=e1; ev[4*k+2]=e2; ev[4*k+3]=e3;
      ss += e0*e0 + e1*e1 + e2*e2 + e3*e3;
    }
    ss += __shfl_xor(ss, 1); ss += __shfl_xor(ss, 2); ss += __shfl_xor(ss, 4);
    float invn = 1.f / fmaxf(sqrtf(ss), 1e-12f);
#pragma unroll
    for (int k = 0; k < 16; k++) es[row][c0 + k] = ev[k]*invn + conv_b[c0 + k];
  }
  float rw1[64];
#pragma unroll
  for (int i = 0; i < 64; i++) rw1[i] = w1[(kh*64 + i)*128 + c];
  float rw2[32];
#pragma unroll
  for (int i = 0; i < 32; i++) rw2[i] = w2[(kh2*32 + i)*64 + o];
  float bb1 = b1[c], bb2 = b2[o];
  __shared__ float hidp[2][4][128];
  __shared__ float hid[4][128];
  __shared__ float outp[4][4][64];
  __syncthreads();
  for (int it = 0; it < 8; it++){
    int rb4 = it*4;
#pragma unroll
    for (int g = 0; g < 4; g++){
      float s = 0.f;
#pragma unroll
      for (int i = 0; i < 64; i++) s += es[rb4 + g][kh*64 + i]*rw1[i];
      hidp[kh][g][c] = s;
    }
    __syncthreads();
#pragma unroll
    for (int gg = 0; gg < 2; gg++){
      int g = kh + 2*gg;
      hid[g][c] = eluf(bb1 + hidp[0][g][c] + hidp[1][g][c]);
    }
    __syncthreads();
#pragma unroll
    for (int g = 0; g < 4; g++){
      float s = 0.f;
#pragma unroll
      for (int i = 0; i < 32; i++) s += hid[g][kh2*32 + i]*rw2[i];
      outp[kh2][g][o] = s;
    }
    __syncthreads();
    { int g = t >> 6;
      out[(size_t)(r0 + rb4 + g)*64 + o] =
        eluf(bb2 + outp[0][g][o] + outp[1][g][o] + outp[2][g][o] + outp[3][g][o]); }
    __syncthreads();
  }
}

// ---------------- E4: pred = rowwise dot of gathered tf/tg ----------------
__global__ __launch_bounds__(256) void k_pred(
    const int* __restrict__ ts, const float4* __restrict__ tf4,
    const float4* __restrict__ tg4, float* __restrict__ out){
  int p = blockIdx.x*16 + (threadIdx.x >> 4);
  int l = threadIdx.x & 15;
  int i = ts[2*p], j = ts[2*p + 1];
  float4 a = tf4[(size_t)i*16 + l], b = tg4[(size_t)j*16 + l];
  float v = a.x*b.x + a.y*b.y + a.z*b.z + a.w*b.w;
  v += __shfl_xor(v, 1); v += __shfl_xor(v, 2);
  v += __shfl_xor(v, 4); v += __shfl_xor(v, 8);
  if (l == 0) out[p] = v;
}

// ---------------- workspace layout ----------------
#define OFF_MASK  ((size_t)0)
#define OFF_X16   ((size_t)8388608)
#define OFF_WT16  ((size_t)20971520)
#define OFF_HT16  ((size_t)21757952)
#define OFF_WH1   ((size_t)30146560)
#define OFF_WH2   ((size_t)30212096)
#define OFF_GMAX  ((size_t)30277632)
#define OFF_C1    ((size_t)30277888)
#define OFF_C2    ((size_t)30343424)
#define OFF_NUM1  ((size_t)30408960)
#define OFF_DEN1  ((size_t)47186176)
#define OFF_GT16  ((size_t)47251712)
#define OFF_WC1L  ((size_t)49348864)
#define OFF_WC2L  ((size_t)49381632)
#define OFF_NUMCP ((size_t)49414400)   // 2 x 8192 x 128 f32 = 8388608
#define OFF_DENCP ((size_t)57803008)   // 2 x 8192 f32 = 65536
#define OFF_TF    ((size_t)57868544)
#define OFF_TG    ((size_t)59965696)

extern "C" void kernel_launch(void* const* d_in, const int* in_sizes, int n_in,
                              void* d_out, int out_size, void* d_ws, size_t ws_size,
                              hipStream_t stream){
  const float* x      = (const float*)d_in[0];
  const int*   adj    = (const int*)d_in[1];
  const int*   ts     = (const int*)d_in[2];
  const float* head_W = (const float*)d_in[3];
  const float* head_a = (const float*)d_in[4];
  const float* head_b = (const float*)d_in[5];
  const float* conv_w = (const float*)d_in[6];
  const float* conv_cb= (const float*)d_in[7];
  const float* conv_a = (const float*)d_in[8];
  const float* conv_b = (const float*)d_in[9];
  const float* tf_w1  = (const float*)d_in[10];
  const float* tf_b1  = (const float*)d_in[11];
  const float* tf_w2  = (const float*)d_in[12];
  const float* tf_b2  = (const float*)d_in[13];
  const float* tg_w1  = (const float*)d_in[14];
  const float* tg_b1  = (const float*)d_in[15];
  const float* tg_w2  = (const float*)d_in[16];
  const float* tg_b2  = (const float*)d_in[17];
  float* outp = (float*)d_out;
  char* ws = (char*)d_ws;

  unsigned* maskw = (unsigned*)(ws + OFF_MASK);
  f16*   x16   = (f16*)(ws + OFF_X16);
  f16*   Wt16  = (f16*)(ws + OFF_WT16);
  f16*   hT16  = (f16*)(ws + OFF_HT16);
  float* wh1   = (float*)(ws + OFF_WH1);
  float* wh2   = (float*)(ws + OFF_WH2);
  unsigned* gmax = (unsigned*)(ws + OFF_GMAX);
  float* c1    = (float*)(ws + OFF_C1);
  float* c2    = (float*)(ws + OFF_C2);
  float* num1  = (float*)(ws + OFF_NUM1);
  float* den1  = (float*)(ws + OFF_DEN1);
  f16*   gT16  = (f16*)(ws + OFF_GT16);
  float* wc1L  = (float*)(ws + OFF_WC1L);
  float* wc2L  = (float*)(ws + OFF_WC2L);
  float* numcp = (float*)(ws + OFF_NUMCP);
  float* dencp = (float*)(ws + OFF_DENCP);
  float* tf    = (float*)(ws + OFF_TF);
  float* tg    = (float*)(ws + OFF_TG);

  // zero only the atomic accumulators (wh1+wh2+gmax)
  hipMemsetAsync(wh1, 0, 131328, stream);

  k_prep   <<<72192, 256, 0, stream>>>((const int4*)adj, maskw, x, x16, head_W, Wt16);
  k_gemm_h <<<dim3(NN/64, DT/128), 256, 0, stream>>>(x16, Wt16, head_a, hT16, wh1, wh2);
  k_rowterms<<<64, 256, 0, stream>>>(wh2, c1, c2, gmax);
  k_agg_head<<<dim3(NN/64, 2), 512, 0, stream>>>(hT16, maskw, wh1, c1, c2, gmax, num1, den1);
  k_merge_conv<<<NN/2, 256, 0, stream>>>(num1, den1, head_b, conv_w, conv_cb, conv_a, gT16, wc1L, wc2L);
  k_agg_conv<<<dim3(NN/64, 2), 512, 0, stream>>>(gT16, maskw, wc1L, wc2L, numcp, dencp);
  k_mlp    <<<dim3(NN/32, 2), 256, 0, stream>>>(numcp, dencp, conv_b,
                                                tf_w1, tf_b1, tf_w2, tf_b2,
                                                tg_w1, tg_b1, tg_w2, tg_b2, tf, tg);
  k_pred   <<<EPAIRS/16, 256, 0, stream>>>(ts, (const float4*)tf, (const float4*)tg, outp);
}

// Round 6
// 965.164 us; speedup vs baseline: 1.0003x; 1.0003x over previous
//
#include <hip/hip_runtime.h>

// GATCL: 2-head GAT (N=8192, D=256) + feature conv (K=129) + GAT(D=128) + 2 MLPs + pair dots.
// R6: occupancy fix. agg kernels use 256-thr blocks with j-split plain-store partials
// (512 blocks = 2-3/CU co-resident to overlap barrier drains; zero atomics in agg).
// XOR-swizzled LDS (0 conflicts), register prefetch, fp16 MFMA 16x16x32, fp32 epilogues.

typedef _Float16 f16;
typedef _Float16 f16x8 __attribute__((ext_vector_type(8)));
typedef float f32x4 __attribute__((ext_vector_type(4)));

#define DEV __device__ __forceinline__
#define L2E 1.4426950408889634f
#define NN 8192
#define IND 768
#define D1 256
#define DT 512
#define D2 128
#define KC 129
#define EPAIRS 100000

#if __has_builtin(__builtin_amdgcn_exp2f)
#define EXP2(x) __builtin_amdgcn_exp2f(x)
#else
#define EXP2(x) exp2f(x)
#endif

DEV float eluf(float x){ return x > 0.f ? x : EXP2(x*L2E) - 1.f; }

// ---------------- P: fused prep = pack(adj->bits) + cast(x->fp16) + Wt transpose ----------------
__global__ __launch_bounds__(256) void k_prep(
    const int4* __restrict__ adj4, unsigned* __restrict__ maskw,
    const float* __restrict__ x, f16* __restrict__ x16,
    const float* __restrict__ W, f16* __restrict__ Wt){
  int b = blockIdx.x, t = threadIdx.x;
  if (b < 65536){
    int idx = b*256 + t;
    int4 v = adj4[idx];
    unsigned n = (unsigned)(v.x > 0) | ((unsigned)(v.y > 0) << 1)
               | ((unsigned)(v.z > 0) << 2) | ((unsigned)(v.w > 0) << 3);
    n |= __shfl_xor(n, 1) << 4;
    n |= __shfl_xor(n, 2) << 8;
    n |= __shfl_xor(n, 4) << 16;
    if ((t & 7) == 0) maskw[idx >> 3] = n;
  } else if (b < 65536 + 6144){
    int i = ((b - 65536)*256 + t)*4;
    float4 v = *(const float4*)(x + i);
    union { f16 h[4]; uint2 u; } p;
    p.h[0]=(f16)v.x; p.h[1]=(f16)v.y; p.h[2]=(f16)v.z; p.h[3]=(f16)v.w;
    *(uint2*)(x16 + i) = p.u;
  } else {
    int np = b - 71680; int h = np >> 8, d = np & 255;
    for (int k = t; k < IND; k += 256)
      Wt[(size_t)np*IND + k] = (f16)W[((size_t)h*IND + k)*D1 + d];
  }
}

// ---------------- G1: h = x @ W' (8192x512), swizzled LDS, prefetch, coalesced hT store ----------------
__global__ __launch_bounds__(256) void k_gemm_h(
    const f16* __restrict__ x16, const f16* __restrict__ Wt,
    const float* __restrict__ head_a,
    f16* __restrict__ hT, float* __restrict__ wh1, float* __restrict__ wh2){
  __shared__ f16 SM[(64 + 128)*64];
  f16* As = SM;
  f16* Bs = SM + 64*64;
  int m0 = blockIdx.x*64, n0 = blockIdx.y*128;
  int t = threadIdx.x, lane = t & 63, w = t >> 6;
  int wi = w >> 1, wd = w & 1;
  int rm = lane & 15, q4 = lane >> 4;
  int drb = t >> 3, gofs = (t & 7)*8;
  int sg8 = (((t & 7) ^ ((t >> 3) & 7))*8);
  f32x4 acc[2][4] = {};
  uint4 preA[2], preB[4];
#pragma unroll
  for (int p = 0; p < 2; p++)
    preA[p] = *(const uint4*)&x16[(size_t)(m0 + p*32 + drb)*IND + gofs];
#pragma unroll
  for (int p = 0; p < 4; p++)
    preB[p] = *(const uint4*)&Wt[(size_t)(n0 + p*32 + drb)*IND + gofs];
  for (int k0 = 0; k0 < IND; k0 += 64){
    __syncthreads();
#pragma unroll
    for (int p = 0; p < 2; p++) *(uint4*)&As[(p*32 + drb)*64 + sg8] = preA[p];
#pragma unroll
    for (int p = 0; p < 4; p++) *(uint4*)&Bs[(p*32 + drb)*64 + sg8] = preB[p];
    __syncthreads();
    if (k0 + 64 < IND){
#pragma unroll
      for (int p = 0; p < 2; p++)
        preA[p] = *(const uint4*)&x16[(size_t)(m0 + p*32 + drb)*IND + k0 + 64 + gofs];
#pragma unroll
      for (int p = 0; p < 4; p++)
        preB[p] = *(const uint4*)&Wt[(size_t)(n0 + p*32 + drb)*IND + k0 + 64 + gofs];
    }
#pragma unroll
    for (int ks = 0; ks < 2; ks++){
      int gl = ks*4 + q4;
      int r0 = wi*32 + rm, r1 = wi*32 + 16 + rm;
      f16x8 a0 = *(const f16x8*)&As[r0*64 + ((gl ^ (r0 & 7))*8)];
      f16x8 a1 = *(const f16x8*)&As[r1*64 + ((gl ^ (r1 & 7))*8)];
#pragma unroll
      for (int fn = 0; fn < 4; fn++){
        int rb = wd*64 + fn*16 + rm;
        f16x8 b = *(const f16x8*)&Bs[rb*64 + ((gl ^ (rb & 7))*8)];
        acc[0][fn] = __builtin_amdgcn_mfma_f32_16x16x32_f16(a0, b, acc[0][fn], 0, 0, 0);
        acc[1][fn] = __builtin_amdgcn_mfma_f32_16x16x32_f16(a1, b, acc[1][fn], 0, 0, 0);
      }
    }
  }
  int quad = lane >> 4, cl = lane & 15;
  int head = n0 >> 8;
  // transpose C into LDS then coalesced hT store (full 128x64 tile)
  f16* T = SM;
  __syncthreads();
#pragma unroll
  for (int fi = 0; fi < 2; fi++)
#pragma unroll
    for (int fn = 0; fn < 4; fn++){
      int d = wd*64 + fn*16 + cl;
      int i = wi*32 + fi*16 + quad*4;
      union { f16 h[4]; uint2 u; } pk;
#pragma unroll
      for (int reg = 0; reg < 4; reg++) pk.h[reg] = (f16)acc[fi][fn][reg];
      *(uint2*)&T[d*72 + i] = pk.u;
    }
  __syncthreads();
  { int row = t >> 1, half = t & 1;
    const f16* src = &T[row*72 + half*32];
    f16* dst = &hT[(size_t)(n0 + row)*NN + m0 + half*32];
#pragma unroll
    for (int q = 0; q < 4; q++)
      *(uint4*)&dst[q*8] = *(const uint4*)&src[q*8];
  }
  float a1v[4], a2v[4];
#pragma unroll
  for (int fn = 0; fn < 4; fn++){
    int d = (n0 & 255) + wd*64 + fn*16 + cl;
    a1v[fn] = head_a[head*DT + d];
    a2v[fn] = head_a[head*DT + D1 + d];
  }
  float p1[2][4], p2[2][4];
#pragma unroll
  for (int fi = 0; fi < 2; fi++)
#pragma unroll
    for (int reg = 0; reg < 4; reg++){
      float s1 = 0.f, s2 = 0.f;
#pragma unroll
      for (int fn = 0; fn < 4; fn++){ s1 += acc[fi][fn][reg]*a1v[fn]; s2 += acc[fi][fn][reg]*a2v[fn]; }
      p1[fi][reg] = s1; p2[fi][reg] = s2;
    }
#pragma unroll
  for (int o = 1; o < 16; o <<= 1){
#pragma unroll
    for (int fi = 0; fi < 2; fi++)
#pragma unroll
      for (int reg = 0; reg < 4; reg++){
        p1[fi][reg] += __shfl_xor(p1[fi][reg], o);
        p2[fi][reg] += __shfl_xor(p2[fi][reg], o);
      }
  }
  if (cl == 0){
#pragma unroll
    for (int fi = 0; fi < 2; fi++)
#pragma unroll
      for (int reg = 0; reg < 4; reg++){
        int mg = m0 + wi*32 + fi*16 + quad*4 + reg;
        atomicAdd(&wh1[head*NN + mg], p1[fi][reg]);
        atomicAdd(&wh2[head*NN + mg], p2[fi][reg]);
      }
  }
}

// ---------------- R: rowterms = colterms + per-head global max of wh2 ----------------
__global__ __launch_bounds__(256) void k_rowterms(const float* __restrict__ wh2,
    float* __restrict__ c1, float* __restrict__ c2, unsigned* __restrict__ gmax){
  int i = blockIdx.x*256 + threadIdx.x;
  float v = wh2[i];
  c1[i] = v*L2E; c2[i] = 0.2f*v*L2E;
  float m = v;
#pragma unroll
  for (int o = 32; o > 0; o >>= 1) m = fmaxf(m, __shfl_xor(m, o));
  if ((threadIdx.x & 63) == 0){
    unsigned bbits = __float_as_uint(m);
    unsigned enc = (bbits & 0x80000000u) ? ~bbits : (bbits | 0x80000000u);
    atomicMax(gmax + (i >> 13), enc);
  }
}

// ---------------- A1: head GAT agg. 256 thr, i64 x D256, j-split 2, plain-store partials ----------------
__global__ __launch_bounds__(256, 3) void k_agg_head(
    const f16* __restrict__ hT, const unsigned* __restrict__ maskw,
    const float* __restrict__ wh1, const float* __restrict__ c1,
    const float* __restrict__ c2, const unsigned* __restrict__ gmaxp,
    float* __restrict__ num1p, float* __restrict__ den1p){
  __shared__ f16 Hs[256*64];   // 32 KB
  __shared__ f16 Ws[64*64];    // 8 KB
  int i0 = blockIdx.x*64;
  int jsp = blockIdx.y, jbase = jsp*4096;
  int head = blockIdx.z;
  const f16* hTh = hT + (size_t)head*D1*NN;
  int t = threadIdx.x, lane = t & 63, w = t >> 6;
  int rm = lane & 15, q4 = lane >> 4;
  int si = t >> 2, sjq = (t & 3)*16;
  unsigned e = gmaxp[head];
  float gmax = __uint_as_float((e & 0x80000000u) ? (e ^ 0x80000000u) : ~e);
  float u = wh1[head*NN + i0 + si];
  float sm = u + gmax;
  float M = (sm > 0.f ? sm : 0.2f*sm)*L2E;   // leaky(wh1+gmax) in log2 units
  float ra = u*L2E - M, rb = 0.2f*u*L2E - M;
  const float* c1h = c1 + head*NN;
  const float* c2h = c2 + head*NN;
  const unsigned* mrowp = maskw + (size_t)(i0 + si)*(NN/32);
  int wg0 = (t & 3)*2;
  float rden = 0.f;
  f32x4 acc[4][4] = {};
  int r_[8], g_[8];
  uint4 pre[8];
#pragma unroll
  for (int p = 0; p < 8; p++){
    int idx = p*256 + t; r_[p] = idx >> 3; g_[p] = idx & 7;
    pre[p] = *(const uint4*)&hTh[(size_t)r_[p]*NN + jbase + g_[p]*8];
  }
  for (int j0 = 0; j0 < 4096; j0 += 64){
    int jg = jbase + j0;
    __syncthreads();
#pragma unroll
    for (int p = 0; p < 8; p++)
      *(uint4*)&Hs[r_[p]*64 + ((g_[p] ^ (r_[p] & 7))*8)] = pre[p];
    // scores: 16 per thread, global c1/c2/mask reads (L1/L2 resident)
    unsigned mb = mrowp[(unsigned)(jg + sjq) >> 5] >> (sjq & 31);
    float ca[16], cb[16];
#pragma unroll
    for (int k = 0; k < 4; k++){
      float4 va = *(const float4*)&c1h[jg + sjq + 4*k];
      float4 vb = *(const float4*)&c2h[jg + sjq + 4*k];
      ca[4*k]=va.x; ca[4*k+1]=va.y; ca[4*k+2]=va.z; ca[4*k+3]=va.w;
      cb[4*k]=vb.x; cb[4*k+1]=vb.y; cb[4*k+2]=vb.z; cb[4*k+3]=vb.w;
    }
    f16x8 wlo, whi;
    float dsum = 0.f;
#pragma unroll
    for (int q = 0; q < 16; q++){
      float s1 = ra + ca[q], s2 = rb + cb[q];
      float wv = EXP2(fmaxf(s1, s2));          // exp(leaky(s)-m) <= 1
      wv = ((mb >> q) & 1u) ? wv : 0.f;
      dsum += wv;
      if (q < 8) wlo[q] = (f16)wv; else whi[q - 8] = (f16)wv;
    }
    *(f16x8*)&Ws[si*64 + ((wg0       ^ (si & 7))*8)] = wlo;
    *(f16x8*)&Ws[si*64 + (((wg0 + 1) ^ (si & 7))*8)] = whi;
    rden += dsum;
    __syncthreads();
    if (j0 + 64 < 4096){
#pragma unroll
      for (int p = 0; p < 8; p++)
        pre[p] = *(const uint4*)&hTh[(size_t)r_[p]*NN + jg + 64 + g_[p]*8];
    }
#pragma unroll
    for (int ks = 0; ks < 2; ks++){
      int gl = ks*4 + q4;
      f16x8 a[4], b[4];
#pragma unroll
      for (int mi = 0; mi < 4; mi++){
        int row = mi*16 + rm;
        a[mi] = *(const f16x8*)&Ws[row*64 + ((gl ^ (row & 7))*8)];
      }
#pragma unroll
      for (int fn = 0; fn < 4; fn++){
        int row = w*64 + fn*16 + rm;
        b[fn] = *(const f16x8*)&Hs[row*64 + ((gl ^ (row & 7))*8)];
      }
#pragma unroll
      for (int mi = 0; mi < 4; mi++)
#pragma unroll
        for (int fn = 0; fn < 4; fn++)
          acc[mi][fn] = __builtin_amdgcn_mfma_f32_16x16x32_f16(a[mi], b[fn], acc[mi][fn], 0, 0, 0);
    }
  }
  rden += __shfl_xor(rden, 1);
  rden += __shfl_xor(rden, 2);
  if ((t & 3) == 0) den1p[(size_t)(jsp*2 + head)*NN + i0 + si] = rden;
  int quad = lane >> 4, cl = lane & 15;
  float* numo = num1p + (size_t)(jsp*2 + head)*NN*D1;
#pragma unroll
  for (int mi = 0; mi < 4; mi++)
#pragma unroll
    for (int fn = 0; fn < 4; fn++){
      int rr = i0 + mi*16 + quad*4;
      int dc = w*64 + fn*16 + cl;
#pragma unroll
      for (int reg = 0; reg < 4; reg++)
        numo[(size_t)(rr + reg)*D1 + dc] = acc[mi][fn][reg];
    }
}

// ---------------- E1: merge head partials -> z -> conv -> gT(fp16) + wc1L/wc2L ----------------
__global__ __launch_bounds__(256) void k_merge_conv(
    const float* __restrict__ num1p, const float* __restrict__ den1p,
    const float* __restrict__ head_b, const float* __restrict__ conv_w,
    const float* __restrict__ conv_cb, const float* __restrict__ conv_a,
    f16* __restrict__ gT, float* __restrict__ wc1L, float* __restrict__ wc2L){
  __shared__ float zrow[2][256];
  __shared__ float cw[KC];
  __shared__ float ca[256];
  __shared__ float red[2][2];
  __shared__ float red2[2][2][2];
  int t = threadIdx.x, g = t >> 7, c = t & 127;
  int r = blockIdx.x*2 + g;
  if (t < KC) cw[t] = conv_w[t];
  ca[t] = conv_a[t];
  float zv0 = 0.f, zv1 = 0.f;
#pragma unroll
  for (int h = 0; h < 2; h++){
    const float* n0 = num1p + ((size_t)(0*2 + h)*NN + r)*D1;
    const float* n1 = num1p + ((size_t)(1*2 + h)*NN + r)*D1;
    float inv = 1.f / (den1p[(size_t)(0*2 + h)*NN + r] + den1p[(size_t)(1*2 + h)*NN + r]);
    float e0 = eluf((n0[c] + n1[c])*inv);
    float e1 = eluf((n0[c + 128] + n1[c + 128])*inv);
    float ss = e0*e0 + e1*e1;
#pragma unroll
    for (int o = 32; o > 0; o >>= 1) ss += __shfl_xor(ss, o);
    if ((t & 63) == 0) red[g][(t >> 6) & 1] = ss;
    __syncthreads();
    float invn = 1.f / fmaxf(sqrtf(red[g][0] + red[g][1]), 1e-12f);
    zv0 += e0*invn + head_b[h*D1 + c];
    zv1 += e1*invn + head_b[h*D1 + 128 + c];
    __syncthreads();
  }
  zrow[g][c]       = eluf(0.5f*zv0);
  zrow[g][c + 128] = eluf(0.5f*zv1);
  __syncthreads();
  float s = conv_cb[0];
  for (int k = 0; k < KC; k++) s += zrow[g][c + k]*cw[k];
  gT[(size_t)c*NN + r] = (f16)s;
  float p1 = s*ca[c], p2 = s*ca[128 + c];
#pragma unroll
  for (int o = 32; o > 0; o >>= 1){ p1 += __shfl_xor(p1, o); p2 += __shfl_xor(p2, o); }
  if ((t & 63) == 0){ red2[g][(t >> 6) & 1][0] = p1; red2[g][(t >> 6) & 1][1] = p2; }
  __syncthreads();
  if ((t & 127) == 0){
    wc1L[r] = (red2[g][0][0] + red2[g][1][0])*L2E;
    wc2L[r] = (red2[g][0][1] + red2[g][1][1])*L2E;
  }
}

// ---------------- A2: conv GAT agg. 256 thr, i64 x D128, j-split 4, plain-store partials ----------------
__global__ __launch_bounds__(256, 4) void k_agg_conv(
    const f16* __restrict__ gT, const unsigned* __restrict__ maskw,
    const float* __restrict__ wc1L, const float* __restrict__ wc2L,
    float* __restrict__ numcp, float* __restrict__ dencp){
  __shared__ f16 Hs[128*64];   // 16 KB
  __shared__ f16 Ws[64*64];    // 8 KB
  int i0 = blockIdx.x*64;
  int jsp = blockIdx.y, jbase = jsp*2048;
  int t = threadIdx.x, lane = t & 63, w = t >> 6;
  int rm = lane & 15, q4 = lane >> 4;
  int si = t >> 2, sjq = (t & 3)*16;
  float ra = wc1L[i0 + si];
  const unsigned* mrowp = maskw + (size_t)(i0 + si)*(NN/32);
  int wg0 = (t & 3)*2;
  float rden = 0.f;
  f32x4 acc[4][2] = {};
  int r_[4], g_[4];
  uint4 pre[4];
#pragma unroll
  for (int p = 0; p < 4; p++){
    int idx = p*256 + t; r_[p] = idx >> 3; g_[p] = idx & 7;
    pre[p] = *(const uint4*)&gT[(size_t)r_[p]*NN + jbase + g_[p]*8];
  }
  for (int j0 = 0; j0 < 2048; j0 += 64){
    int jg = jbase + j0;
    __syncthreads();
#pragma unroll
    for (int p = 0; p < 4; p++)
      *(uint4*)&Hs[r_[p]*64 + ((g_[p] ^ (r_[p] & 7))*8)] = pre[p];
    unsigned mb = mrowp[(unsigned)(jg + sjq) >> 5] >> (sjq & 31);
    float cc[16];
#pragma unroll
    for (int k = 0; k < 4; k++){
      float4 va = *(const float4*)&wc2L[jg + sjq + 4*k];
      cc[4*k]=va.x; cc[4*k+1]=va.y; cc[4*k+2]=va.z; cc[4*k+3]=va.w;
    }
    f16x8 wlo, whi;
    float dsum = 0.f;
#pragma unroll
    for (int q = 0; q < 16; q++){
      float sL = ra + cc[q];                   // s*log2e
      float t2 = EXP2(sL);                     // e^s
      float wv = sL > 0.f ? t2 : EXP2((t2 - 1.f)*L2E);  // exp(elu(s))
      wv = ((mb >> q) & 1u) ? wv : 0.f;
      dsum += wv;
      if (q < 8) wlo[q] = (f16)wv; else whi[q - 8] = (f16)wv;
    }
    *(f16x8*)&Ws[si*64 + ((wg0       ^ (si & 7))*8)] = wlo;
    *(f16x8*)&Ws[si*64 + (((wg0 + 1) ^ (si & 7))*8)] = whi;
    rden += dsum;
    __syncthreads();
    if (j0 + 64 < 2048){
#pragma unroll
      for (int p = 0; p < 4; p++)
        pre[p] = *(const uint4*)&gT[(size_t)r_[p]*NN + jg + 64 + g_[p]*8];
    }
#pragma unroll
    for (int ks = 0; ks < 2; ks++){
      int gl = ks*4 + q4;
      f16x8 a[4], b[2];
#pragma unroll
      for (int mi = 0; mi < 4; mi++){
        int row = mi*16 + rm;
        a[mi] = *(const f16x8*)&Ws[row*64 + ((gl ^ (row & 7))*8)];
      }
#pragma unroll
      for (int fn = 0; fn < 2; fn++){
        int row = w*32 + fn*16 + rm;
        b[fn] = *(const f16x8*)&Hs[row*64 + ((gl ^ (row & 7))*8)];
      }
#pragma unroll
      for (int mi = 0; mi < 4; mi++)
#pragma unroll
        for (int fn = 0; fn < 2; fn++)
          acc[mi][fn] = __builtin_amdgcn_mfma_f32_16x16x32_f16(a[mi], b[fn], acc[mi][fn], 0, 0, 0);
    }
  }
  rden += __shfl_xor(rden, 1);
  rden += __shfl_xor(rden, 2);
  if ((t & 3) == 0) dencp[(size_t)jsp*NN + i0 + si] = rden;
  int quad = lane >> 4, cl = lane & 15;
  float* numo = numcp + (size_t)jsp*NN*D2;
#pragma unroll
  for (int mi = 0; mi < 4; mi++)
#pragma unroll
    for (int fn = 0; fn < 2; fn++){
      int rr = i0 + mi*16 + quad*4;
      int dc = w*32 + fn*16 + cl;
#pragma unroll
      for (int reg = 0; reg < 4; reg++)
        numo[(size_t)(rr + reg)*D2 + dc] = acc[mi][fn][reg];
    }
}

// ---------------- E3: fused embed (merge 4 conv partials) + two MLPs ----------------
__global__ __launch_bounds__(256) void k_mlp(
    const float* __restrict__ numcp, const float* __restrict__ dencp,
    const float* __restrict__ conv_b,
    const float* __restrict__ fw1, const float* __restrict__ fb1,
    const float* __restrict__ fw2, const float* __restrict__ fb2,
    const float* __restrict__ gw1, const float* __restrict__ gb1,
    const float* __restrict__ gw2, const float* __restrict__ gb2,
    float* __restrict__ tf, float* __restrict__ tg){
  const float* w1 = blockIdx.y ? gw1 : fw1;
  const float* b1 = blockIdx.y ? gb1 : fb1;
  const float* w2 = blockIdx.y ? gw2 : fw2;
  const float* b2 = blockIdx.y ? gb2 : fb2;
  float* out = blockIdx.y ? tg : tf;
  int t = threadIdx.x;
  int c = t & 127, kh = t >> 7;
  int o = t & 63, kh2 = t >> 6;
  int r0 = blockIdx.x*32;
  __shared__ float es[32][132];
  { int row = t >> 3, c0 = (t & 7)*16;
    int rg = r0 + row;
    float inv = 1.f / (dencp[rg] + dencp[NN + rg] + dencp[2*NN + rg] + dencp[3*NN + rg]);
    float ev[16]; float ss = 0.f;
#pragma unroll
    for (int k = 0; k < 4; k++){
      float4 v0 = *(const float4*)&numcp[(size_t)rg*D2 + c0 + 4*k];
      float4 v1 = *(const float4*)&numcp[((size_t)NN + rg)*D2 + c0 + 4*k];
      float4 v2 = *(const float4*)&numcp[((size_t)2*NN + rg)*D2 + c0 + 4*k];
      float4 v3 = *(const float4*)&numcp[((size_t)3*NN + rg)*D2 + c0 + 4*k];
      float e0 = eluf((v0.x + v1.x + v2.x + v3.x)*inv);
      float e1 = eluf((v0.y + v1.y + v2.y + v3.y)*inv);
      float e2 = eluf((v0.z + v1.z + v2.z + v3.z)*inv);
      float e3 = eluf((v0.w + v1.w + v2.w + v3.w)*inv);
      ev[4*k]=e0; ev[4*k+1]=e1; ev[4*k+2]=e2; ev[4*k+3]=e3;
      ss += e0*e0 + e1*e1 + e2*e2 + e3*e3;
    }
    ss += __shfl_xor(ss, 1); ss += __shfl_xor(ss, 2); ss += __shfl_xor(ss, 4);
    float invn = 1.f / fmaxf(sqrtf(ss), 1e-12f);
#pragma unroll
    for (int k = 0; k < 16; k++) es[row][c0 + k] = ev[k]*invn + conv_b[c0 + k];
  }
  float rw1[64];
#pragma unroll
  for (int i = 0; i < 64; i++) rw1[i] = w1[(kh*64 + i)*128 + c];
  float rw2[32];
#pragma unroll
  for (int i = 0; i < 32; i++) rw2[i] = w2[(kh2*32 + i)*64 + o];
  float bb1 = b1[c], bb2 = b2[o];
  __shared__ float hidp[2][4][128];
  __shared__ float hid[4][128];
  __shared__ float outp[4][4][64];
  __syncthreads();
  for (int it = 0; it < 8; it++){
    int rb4 = it*4;
#pragma unroll
    for (int g = 0; g < 4; g++){
      float s = 0.f;
#pragma unroll
      for (int i = 0; i < 64; i++) s += es[rb4 + g][kh*64 + i]*rw1[i];
      hidp[kh][g][c] = s;
    }
    __syncthreads();
#pragma unroll
    for (int gg = 0; gg < 2; gg++){
      int g = kh + 2*gg;
      hid[g][c] = eluf(bb1 + hidp[0][g][c] + hidp[1][g][c]);
    }
    __syncthreads();
#pragma unroll
    for (int g = 0; g < 4; g++){
      float s = 0.f;
#pragma unroll
      for (int i = 0; i < 32; i++) s += hid[g][kh2*32 + i]*rw2[i];
      outp[kh2][g][o] = s;
    }
    __syncthreads();
    { int g = t >> 6;
      out[(size_t)(r0 + rb4 + g)*64 + o] =
        eluf(bb2 + outp[0][g][o] + outp[1][g][o] + outp[2][g][o] + outp[3][g][o]); }
    __syncthreads();
  }
}

// ---------------- E4: pred = rowwise dot of gathered tf/tg ----------------
__global__ __launch_bounds__(256) void k_pred(
    const int* __restrict__ ts, const float4* __restrict__ tf4,
    const float4* __restrict__ tg4, float* __restrict__ out){
  int p = blockIdx.x*16 + (threadIdx.x >> 4);
  int l = threadIdx.x & 15;
  int i = ts[2*p], j = ts[2*p + 1];
  float4 a = tf4[(size_t)i*16 + l], b = tg4[(size_t)j*16 + l];
  float v = a.x*b.x + a.y*b.y + a.z*b.z + a.w*b.w;
  v += __shfl_xor(v, 1); v += __shfl_xor(v, 2);
  v += __shfl_xor(v, 4); v += __shfl_xor(v, 8);
  if (l == 0) out[p] = v;
}

// ---------------- workspace layout (temporal aliasing; peak ~52.9 MB) ----------------
#define OFF_MASK  ((size_t)0)          // 8 MB, live: prep -> agg_conv
#define OFF_X16   ((size_t)8388608)    // 12.6 MB, dead after gemm_h
#define OFF_WT16  ((size_t)20971520)   // 0.8 MB, dead after gemm_h
#define OFF_NUM1P ((size_t)8388608)    // 33.5 MB (2jsp x 2head x 8192 x 256), aliases X16/WT16
#define OFF_NUMCP ((size_t)8388608)    // 16.8 MB (4jsp x 8192 x 128), aliases NUM1P (dead by then)
#define OFF_HT16  ((size_t)41943040)   // 8.4 MB, dead after agg_head
#define OFF_DENCP ((size_t)41943040)   // 131 KB, aliases HT16
#define OFF_TF    ((size_t)42074112)   // 2 MB, aliases HT16
#define OFF_TG    ((size_t)44171264)   // 2 MB, aliases HT16
#define OFF_WH1   ((size_t)50331648)
#define OFF_WH2   ((size_t)50397184)
#define OFF_GMAX  ((size_t)50462720)
#define OFF_C1    ((size_t)50462976)
#define OFF_C2    ((size_t)50528512)
#define OFF_DEN1P ((size_t)50594048)   // 131 KB
#define OFF_GT16  ((size_t)50725120)   // 2 MB
#define OFF_WC1L  ((size_t)52822272)
#define OFF_WC2L  ((size_t)52855040)

extern "C" void kernel_launch(void* const* d_in, const int* in_sizes, int n_in,
                              void* d_out, int out_size, void* d_ws, size_t ws_size,
                              hipStream_t stream){
  const float* x      = (const float*)d_in[0];
  const int*   adj    = (const int*)d_in[1];
  const int*   ts     = (const int*)d_in[2];
  const float* head_W = (const float*)d_in[3];
  const float* head_a = (const float*)d_in[4];
  const float* head_b = (const float*)d_in[5];
  const float* conv_w = (const float*)d_in[6];
  const float* conv_cb= (const float*)d_in[7];
  const float* conv_a = (const float*)d_in[8];
  const float* conv_b = (const float*)d_in[9];
  const float* tf_w1  = (const float*)d_in[10];
  const float* tf_b1  = (const float*)d_in[11];
  const float* tf_w2  = (const float*)d_in[12];
  const float* tf_b2  = (const float*)d_in[13];
  const float* tg_w1  = (const float*)d_in[14];
  const float* tg_b1  = (const float*)d_in[15];
  const float* tg_w2  = (const float*)d_in[16];
  const float* tg_b2  = (const float*)d_in[17];
  float* outp = (float*)d_out;
  char* ws = (char*)d_ws;

  unsigned* maskw = (unsigned*)(ws + OFF_MASK);
  f16*   x16   = (f16*)(ws + OFF_X16);
  f16*   Wt16  = (f16*)(ws + OFF_WT16);
  f16*   hT16  = (f16*)(ws + OFF_HT16);
  float* wh1   = (float*)(ws + OFF_WH1);
  float* wh2   = (float*)(ws + OFF_WH2);
  unsigned* gmax = (unsigned*)(ws + OFF_GMAX);
  float* c1    = (float*)(ws + OFF_C1);
  float* c2    = (float*)(ws + OFF_C2);
  float* num1p = (float*)(ws + OFF_NUM1P);
  float* den1p = (float*)(ws + OFF_DEN1P);
  f16*   gT16  = (f16*)(ws + OFF_GT16);
  float* wc1L  = (float*)(ws + OFF_WC1L);
  float* wc2L  = (float*)(ws + OFF_WC2L);
  float* numcp = (float*)(ws + OFF_NUMCP);
  float* dencp = (float*)(ws + OFF_DENCP);
  float* tf    = (float*)(ws + OFF_TF);
  float* tg    = (float*)(ws + OFF_TG);

  // zero only the atomic accumulators (wh1+wh2+gmax, contiguous)
  hipMemsetAsync(wh1, 0, 131328, stream);

  k_prep   <<<72192, 256, 0, stream>>>((const int4*)adj, maskw, x, x16, head_W, Wt16);
  k_gemm_h <<<dim3(NN/64, DT/128), 256, 0, stream>>>(x16, Wt16, head_a, hT16, wh1, wh2);
  k_rowterms<<<64, 256, 0, stream>>>(wh2, c1, c2, gmax);
  k_agg_head<<<dim3(NN/64, 2, 2), 256, 0, stream>>>(hT16, maskw, wh1, c1, c2, gmax, num1p, den1p);
  k_merge_conv<<<NN/2, 256, 0, stream>>>(num1p, den1p, head_b, conv_w, conv_cb, conv_a, gT16, wc1L, wc2L);
  k_agg_conv<<<dim3(NN/64, 4), 256, 0, stream>>>(gT16, maskw, wc1L, wc2L, numcp, dencp);
  k_mlp    <<<dim3(NN/32, 2), 256, 0, stream>>>(numcp, dencp, conv_b,
                                                tf_w1, tf_b1, tf_w2, tf_b2,
                                                tg_w1, tg_b1, tg_w2, tg_b2, tf, tg);
  k_pred   <<<EPAIRS/16, 256, 0, stream>>>(ts, (const float4*)tf, (const float4*)tg, outp);
}

// Round 7
// 748.674 us; speedup vs baseline: 1.2895x; 1.2892x over previous
//
#include <hip/hip_runtime.h>

// GATCL: 2-head GAT (N=8192, D=256) + feature conv (K=129) + GAT(D=128) + 2 MLPs + pair dots.
// R7: revert agg kernels to the measured-fast K2 structure (direct global->LDS staging,
// stride-72 LDS, atomicAdd merge, no launch-bounds cap, no manual prefetch), with j-split
// bumped 2->4 on agg_head for occupancy. Keep fused prep / fixed gemm_h / fused mlp / f4 pred.

typedef _Float16 f16;
typedef _Float16 f16x8 __attribute__((ext_vector_type(8)));
typedef float f32x4 __attribute__((ext_vector_type(4)));

#define DEV __device__ __forceinline__
#define L2E 1.4426950408889634f
#define NN 8192
#define IND 768
#define D1 256
#define DT 512
#define D2 128
#define KC 129
#define EPAIRS 100000

#if __has_builtin(__builtin_amdgcn_exp2f)
#define EXP2(x) __builtin_amdgcn_exp2f(x)
#else
#define EXP2(x) exp2f(x)
#endif

DEV float eluf(float x){ return x > 0.f ? x : EXP2(x*L2E) - 1.f; }

// ---------------- P: fused prep = pack(adj->bits) + cast(x->fp16) + Wt transpose ----------------
__global__ __launch_bounds__(256) void k_prep(
    const int4* __restrict__ adj4, unsigned* __restrict__ maskw,
    const float* __restrict__ x, f16* __restrict__ x16,
    const float* __restrict__ W, f16* __restrict__ Wt){
  int b = blockIdx.x, t = threadIdx.x;
  if (b < 65536){
    int idx = b*256 + t;
    int4 v = adj4[idx];
    unsigned n = (unsigned)(v.x > 0) | ((unsigned)(v.y > 0) << 1)
               | ((unsigned)(v.z > 0) << 2) | ((unsigned)(v.w > 0) << 3);
    n |= __shfl_xor(n, 1) << 4;
    n |= __shfl_xor(n, 2) << 8;
    n |= __shfl_xor(n, 4) << 16;
    if ((t & 7) == 0) maskw[idx >> 3] = n;
  } else if (b < 65536 + 6144){
    int i = ((b - 65536)*256 + t)*4;
    float4 v = *(const float4*)(x + i);
    union { f16 h[4]; uint2 u; } p;
    p.h[0]=(f16)v.x; p.h[1]=(f16)v.y; p.h[2]=(f16)v.z; p.h[3]=(f16)v.w;
    *(uint2*)(x16 + i) = p.u;
  } else {
    int np = b - 71680; int h = np >> 8, d = np & 255;
    for (int k = t; k < IND; k += 256)
      Wt[(size_t)np*IND + k] = (f16)W[((size_t)h*IND + k)*D1 + d];
  }
}

// ---------------- G1: h = x @ W' (8192x512), swizzled LDS, prefetch, coalesced hT store ----------------
__global__ __launch_bounds__(256) void k_gemm_h(
    const f16* __restrict__ x16, const f16* __restrict__ Wt,
    const float* __restrict__ head_a,
    f16* __restrict__ hT, float* __restrict__ wh1, float* __restrict__ wh2){
  __shared__ f16 SM[(64 + 128)*64];
  f16* As = SM;
  f16* Bs = SM + 64*64;
  int m0 = blockIdx.x*64, n0 = blockIdx.y*128;
  int t = threadIdx.x, lane = t & 63, w = t >> 6;
  int wi = w >> 1, wd = w & 1;
  int rm = lane & 15, q4 = lane >> 4;
  int drb = t >> 3, gofs = (t & 7)*8;
  int sg8 = (((t & 7) ^ ((t >> 3) & 7))*8);
  f32x4 acc[2][4] = {};
  uint4 preA[2], preB[4];
#pragma unroll
  for (int p = 0; p < 2; p++)
    preA[p] = *(const uint4*)&x16[(size_t)(m0 + p*32 + drb)*IND + gofs];
#pragma unroll
  for (int p = 0; p < 4; p++)
    preB[p] = *(const uint4*)&Wt[(size_t)(n0 + p*32 + drb)*IND + gofs];
  for (int k0 = 0; k0 < IND; k0 += 64){
    __syncthreads();
#pragma unroll
    for (int p = 0; p < 2; p++) *(uint4*)&As[(p*32 + drb)*64 + sg8] = preA[p];
#pragma unroll
    for (int p = 0; p < 4; p++) *(uint4*)&Bs[(p*32 + drb)*64 + sg8] = preB[p];
    __syncthreads();
    if (k0 + 64 < IND){
#pragma unroll
      for (int p = 0; p < 2; p++)
        preA[p] = *(const uint4*)&x16[(size_t)(m0 + p*32 + drb)*IND + k0 + 64 + gofs];
#pragma unroll
      for (int p = 0; p < 4; p++)
        preB[p] = *(const uint4*)&Wt[(size_t)(n0 + p*32 + drb)*IND + k0 + 64 + gofs];
    }
#pragma unroll
    for (int ks = 0; ks < 2; ks++){
      int gl = ks*4 + q4;
      int r0 = wi*32 + rm, r1 = wi*32 + 16 + rm;
      f16x8 a0 = *(const f16x8*)&As[r0*64 + ((gl ^ (r0 & 7))*8)];
      f16x8 a1 = *(const f16x8*)&As[r1*64 + ((gl ^ (r1 & 7))*8)];
#pragma unroll
      for (int fn = 0; fn < 4; fn++){
        int rb = wd*64 + fn*16 + rm;
        f16x8 b = *(const f16x8*)&Bs[rb*64 + ((gl ^ (rb & 7))*8)];
        acc[0][fn] = __builtin_amdgcn_mfma_f32_16x16x32_f16(a0, b, acc[0][fn], 0, 0, 0);
        acc[1][fn] = __builtin_amdgcn_mfma_f32_16x16x32_f16(a1, b, acc[1][fn], 0, 0, 0);
      }
    }
  }
  int quad = lane >> 4, cl = lane & 15;
  int head = n0 >> 8;
  // transpose C into LDS then coalesced hT store (full 128x64 tile)
  f16* T = SM;
  __syncthreads();
#pragma unroll
  for (int fi = 0; fi < 2; fi++)
#pragma unroll
    for (int fn = 0; fn < 4; fn++){
      int d = wd*64 + fn*16 + cl;
      int i = wi*32 + fi*16 + quad*4;
      union { f16 h[4]; uint2 u; } pk;
#pragma unroll
      for (int reg = 0; reg < 4; reg++) pk.h[reg] = (f16)acc[fi][fn][reg];
      *(uint2*)&T[d*72 + i] = pk.u;
    }
  __syncthreads();
  { int row = t >> 1, half = t & 1;
    const f16* src = &T[row*72 + half*32];
    f16* dst = &hT[(size_t)(n0 + row)*NN + m0 + half*32];
#pragma unroll
    for (int q = 0; q < 4; q++)
      *(uint4*)&dst[q*8] = *(const uint4*)&src[q*8];
  }
  float a1v[4], a2v[4];
#pragma unroll
  for (int fn = 0; fn < 4; fn++){
    int d = (n0 & 255) + wd*64 + fn*16 + cl;
    a1v[fn] = head_a[head*DT + d];
    a2v[fn] = head_a[head*DT + D1 + d];
  }
  float p1[2][4], p2[2][4];
#pragma unroll
  for (int fi = 0; fi < 2; fi++)
#pragma unroll
    for (int reg = 0; reg < 4; reg++){
      float s1 = 0.f, s2 = 0.f;
#pragma unroll
      for (int fn = 0; fn < 4; fn++){ s1 += acc[fi][fn][reg]*a1v[fn]; s2 += acc[fi][fn][reg]*a2v[fn]; }
      p1[fi][reg] = s1; p2[fi][reg] = s2;
    }
#pragma unroll
  for (int o = 1; o < 16; o <<= 1){
#pragma unroll
    for (int fi = 0; fi < 2; fi++)
#pragma unroll
      for (int reg = 0; reg < 4; reg++){
        p1[fi][reg] += __shfl_xor(p1[fi][reg], o);
        p2[fi][reg] += __shfl_xor(p2[fi][reg], o);
      }
  }
  if (cl == 0){
#pragma unroll
    for (int fi = 0; fi < 2; fi++)
#pragma unroll
      for (int reg = 0; reg < 4; reg++){
        int mg = m0 + wi*32 + fi*16 + quad*4 + reg;
        atomicAdd(&wh1[head*NN + mg], p1[fi][reg]);
        atomicAdd(&wh2[head*NN + mg], p2[fi][reg]);
      }
  }
}

// ---------------- R: rowterms = colterms + per-head global max of wh2 ----------------
__global__ __launch_bounds__(256) void k_rowterms(const float* __restrict__ wh2,
    float* __restrict__ c1, float* __restrict__ c2, unsigned* __restrict__ gmax){
  int i = blockIdx.x*256 + threadIdx.x;
  float v = wh2[i];
  c1[i] = v*L2E; c2[i] = 0.2f*v*L2E;
  float m = v;
#pragma unroll
  for (int o = 32; o > 0; o >>= 1) m = fmaxf(m, __shfl_xor(m, o));
  if ((threadIdx.x & 63) == 0){
    unsigned bbits = __float_as_uint(m);
    unsigned enc = (bbits & 0x80000000u) ? ~bbits : (bbits | 0x80000000u);
    atomicMax(gmax + (i >> 13), enc);
  }
}

// ---------------- A1: head GAT aggregation (K2 structure). i-tile 64, full D=256, j-split 4 ----------------
__global__ __launch_bounds__(256) void k_agg_head(
    const f16* __restrict__ hT, const unsigned* __restrict__ maskw,
    const float* __restrict__ wh1, const float* __restrict__ c1,
    const float* __restrict__ c2, const unsigned* __restrict__ gmaxp,
    float* __restrict__ num, float* __restrict__ den){
  __shared__ f16 Hs[256*72];
  __shared__ f16 Ws[64*72];
  __shared__ float rowa[64], rowb[64];
  int head = blockIdx.z;
  int i0 = blockIdx.x*64;
  int jbase = blockIdx.y*2048;
  const f16* hTh = hT + (size_t)head*D1*NN;
  int t = threadIdx.x, lane = t & 63, w = t >> 6;
  int rm = lane & 15, qm = (lane >> 4)*8;
  if (t < 64){
    unsigned e = gmaxp[head];
    float gmax = __uint_as_float((e & 0x80000000u) ? (e ^ 0x80000000u) : ~e);
    float u = wh1[head*NN + i0 + t];
    float sm = u + gmax;
    float M = (sm > 0.f ? sm : 0.2f*sm)*L2E;   // leaky(wh1+gmax) in log2 units
    rowa[t] = u*L2E - M;
    rowb[t] = 0.2f*u*L2E - M;
  }
  __syncthreads();
  int si = t >> 2, sjq = (t & 3)*16;
  float ra = rowa[si], rb = rowb[si];
  const float* c1h = c1 + head*NN;
  const float* c2h = c2 + head*NN;
  const unsigned* mrowp = maskw + (size_t)(i0 + si)*(NN/32);
  float rden = 0.f;
  f32x4 acc[4][4] = {};
  for (int j0 = 0; j0 < 2048; j0 += 64){
    int jg = jbase + j0;
    // stage Hs[d=256][j=64] (global->reg->LDS, compiler-scheduled)
#pragma unroll
    for (int p = 0; p < 8; p++){
      int idx = p*256 + t, dr = idx >> 3, cc = (idx & 7)*8;
      *(uint4*)&Hs[dr*72 + cc] = *(const uint4*)&hTh[(size_t)dr*NN + jg + cc];
    }
    // scores: direct global reads (L1/L2-resident), no staging dependency
    unsigned mb = mrowp[(unsigned)(jg + sjq) >> 5] >> (sjq & 31);
    float ca[16], cb[16];
#pragma unroll
    for (int k = 0; k < 4; k++){
      float4 va = *(const float4*)&c1h[jg + sjq + 4*k];
      float4 vb = *(const float4*)&c2h[jg + sjq + 4*k];
      ca[4*k]=va.x; ca[4*k+1]=va.y; ca[4*k+2]=va.z; ca[4*k+3]=va.w;
      cb[4*k]=vb.x; cb[4*k+1]=vb.y; cb[4*k+2]=vb.z; cb[4*k+3]=vb.w;
    }
    f16x8 wlo, whi;
    float dsum = 0.f;
#pragma unroll
    for (int q = 0; q < 16; q++){
      float s1 = ra + ca[q], s2 = rb + cb[q];
      float wv = EXP2(fmaxf(s1, s2));          // exp(leaky(s)-m) <= 1
      wv = ((mb >> q) & 1u) ? wv : 0.f;
      dsum += wv;
      if (q < 8) wlo[q] = (f16)wv; else whi[q - 8] = (f16)wv;
    }
    *(f16x8*)&Ws[si*72 + sjq]     = wlo;
    *(f16x8*)&Ws[si*72 + sjq + 8] = whi;
    dsum += __shfl_xor(dsum, 1);
    dsum += __shfl_xor(dsum, 2);
    rden += dsum;
    __syncthreads();
    // MFMA: wave w owns d-range w*64..w*64+63, all 64 i
#pragma unroll
    for (int ks = 0; ks < 2; ks++){
      f16x8 a[4], b[4];
#pragma unroll
      for (int mi = 0; mi < 4; mi++) a[mi] = *(const f16x8*)&Ws[(mi*16 + rm)*72 + ks*32 + qm];
#pragma unroll
      for (int fn = 0; fn < 4; fn++) b[fn] = *(const f16x8*)&Hs[(w*64 + fn*16 + rm)*72 + ks*32 + qm];
#pragma unroll
      for (int mi = 0; mi < 4; mi++)
#pragma unroll
        for (int fn = 0; fn < 4; fn++)
          acc[mi][fn] = __builtin_amdgcn_mfma_f32_16x16x32_f16(a[mi], b[fn], acc[mi][fn], 0, 0, 0);
    }
    __syncthreads();
  }
  if ((t & 3) == 0) atomicAdd(&den[head*NN + i0 + si], rden);
  int quad = lane >> 4, cl = lane & 15;
#pragma unroll
  for (int mi = 0; mi < 4; mi++)
#pragma unroll
    for (int fn = 0; fn < 4; fn++){
      int rr = i0 + mi*16 + quad*4;
      int dc = w*64 + fn*16 + cl;
#pragma unroll
      for (int reg = 0; reg < 4; reg++)
        atomicAdd(&num[((size_t)head*NN + rr + reg)*D1 + dc], acc[mi][fn][reg]);
    }
}

// ---------------- E1: merge heads -> z -> conv -> gT(fp16) + wc1L/wc2L ----------------
__global__ __launch_bounds__(256) void k_merge_conv(
    const float* __restrict__ num, const float* __restrict__ den,
    const float* __restrict__ head_b, const float* __restrict__ conv_w,
    const float* __restrict__ conv_cb, const float* __restrict__ conv_a,
    f16* __restrict__ gT, float* __restrict__ wc1L, float* __restrict__ wc2L){
  __shared__ float zrow[2][256];
  __shared__ float cw[KC];
  __shared__ float ca[256];
  __shared__ float red[2][2];
  __shared__ float red2[2][2][2];
  int t = threadIdx.x, g = t >> 7, c = t & 127;
  int r = blockIdx.x*2 + g;
  if (t < KC) cw[t] = conv_w[t];
  ca[t] = conv_a[t];
  float zv0 = 0.f, zv1 = 0.f;
#pragma unroll
  for (int h = 0; h < 2; h++){
    const float* nr = num + ((size_t)h*NN + r)*D1;
    float inv = 1.f / den[h*NN + r];
    float e0 = eluf(nr[c]*inv);
    float e1 = eluf(nr[c + 128]*inv);
    float ss = e0*e0 + e1*e1;
#pragma unroll
    for (int o = 32; o > 0; o >>= 1) ss += __shfl_xor(ss, o);
    if ((t & 63) == 0) red[g][(t >> 6) & 1] = ss;
    __syncthreads();
    float invn = 1.f / fmaxf(sqrtf(red[g][0] + red[g][1]), 1e-12f);
    zv0 += e0*invn + head_b[h*D1 + c];
    zv1 += e1*invn + head_b[h*D1 + 128 + c];
    __syncthreads();
  }
  zrow[g][c]       = eluf(0.5f*zv0);
  zrow[g][c + 128] = eluf(0.5f*zv1);
  __syncthreads();
  float s = conv_cb[0];
  for (int k = 0; k < KC; k++) s += zrow[g][c + k]*cw[k];
  gT[(size_t)c*NN + r] = (f16)s;
  float p1 = s*ca[c], p2 = s*ca[128 + c];
#pragma unroll
  for (int o = 32; o > 0; o >>= 1){ p1 += __shfl_xor(p1, o); p2 += __shfl_xor(p2, o); }
  if ((t & 63) == 0){ red2[g][(t >> 6) & 1][0] = p1; red2[g][(t >> 6) & 1][1] = p2; }
  __syncthreads();
  if ((t & 127) == 0){
    wc1L[r] = (red2[g][0][0] + red2[g][1][0])*L2E;
    wc2L[r] = (red2[g][0][1] + red2[g][1][1])*L2E;
  }
}

// ---------------- A2: conv GAT aggregation (K2 structure, elu scores, m=0), j-split 8 ----------------
__global__ __launch_bounds__(256) void k_agg_conv(
    const f16* __restrict__ gT, const unsigned* __restrict__ maskw,
    const float* __restrict__ wc1L, const float* __restrict__ wc2L,
    float* __restrict__ num, float* __restrict__ den){
  __shared__ f16 Hs[128*72];
  __shared__ f16 Ws[64*72];
  __shared__ float rowc[64];
  int i0 = blockIdx.x*64;
  int jbase = blockIdx.y*1024;
  int t = threadIdx.x, lane = t & 63, w = t >> 6;
  int rm = lane & 15, qm = (lane >> 4)*8;
  if (t < 64) rowc[t] = wc1L[i0 + t];
  __syncthreads();
  int si = t >> 2, sjq = (t & 3)*16;
  float ra = rowc[si];
  const unsigned* mrowp = maskw + (size_t)(i0 + si)*(NN/32);
  float rden = 0.f;
  f32x4 acc[4][2] = {};
  for (int j0 = 0; j0 < 1024; j0 += 64){
    int jg = jbase + j0;
#pragma unroll
    for (int p = 0; p < 4; p++){
      int idx = p*256 + t, dr = idx >> 3, cc = (idx & 7)*8;
      *(uint4*)&Hs[dr*72 + cc] = *(const uint4*)&gT[(size_t)dr*NN + jg + cc];
    }
    unsigned mb = mrowp[(unsigned)(jg + sjq) >> 5] >> (sjq & 31);
    float cc[16];
#pragma unroll
    for (int k = 0; k < 4; k++){
      float4 va = *(const float4*)&wc2L[jg + sjq + 4*k];
      cc[4*k]=va.x; cc[4*k+1]=va.y; cc[4*k+2]=va.z; cc[4*k+3]=va.w;
    }
    f16x8 wlo, whi;
    float dsum = 0.f;
#pragma unroll
    for (int q = 0; q < 16; q++){
      float sL = ra + cc[q];                   // s*log2e
      float t2 = EXP2(sL);                     // e^s
      float wv = sL > 0.f ? t2 : EXP2((t2 - 1.f)*L2E);  // exp(elu(s))
      wv = ((mb >> q) & 1u) ? wv : 0.f;
      dsum += wv;
      if (q < 8) wlo[q] = (f16)wv; else whi[q - 8] = (f16)wv;
    }
    *(f16x8*)&Ws[si*72 + sjq]     = wlo;
    *(f16x8*)&Ws[si*72 + sjq + 8] = whi;
    dsum += __shfl_xor(dsum, 1);
    dsum += __shfl_xor(dsum, 2);
    rden += dsum;
    __syncthreads();
    // wave w owns d-range w*32..w*32+31, all 64 i
#pragma unroll
    for (int ks = 0; ks < 2; ks++){
      f16x8 a[4], b[2];
#pragma unroll
      for (int mi = 0; mi < 4; mi++) a[mi] = *(const f16x8*)&Ws[(mi*16 + rm)*72 + ks*32 + qm];
#pragma unroll
      for (int fn = 0; fn < 2; fn++) b[fn] = *(const f16x8*)&Hs[(w*32 + fn*16 + rm)*72 + ks*32 + qm];
#pragma unroll
      for (int mi = 0; mi < 4; mi++)
#pragma unroll
        for (int fn = 0; fn < 2; fn++)
          acc[mi][fn] = __builtin_amdgcn_mfma_f32_16x16x32_f16(a[mi], b[fn], acc[mi][fn], 0, 0, 0);
    }
    __syncthreads();
  }
  if ((t & 3) == 0) atomicAdd(&den[i0 + si], rden);
  int quad = lane >> 4, cl = lane & 15;
#pragma unroll
  for (int mi = 0; mi < 4; mi++)
#pragma unroll
    for (int fn = 0; fn < 2; fn++){
      int rr = i0 + mi*16 + quad*4;
      int dc = w*32 + fn*16 + cl;
#pragma unroll
      for (int reg = 0; reg < 4; reg++)
        atomicAdd(&num[(size_t)(rr + reg)*D2 + dc], acc[mi][fn][reg]);
    }
}

// ---------------- E3: fused embed + two 128->128->64 elu MLPs, 32 rows/block ----------------
__global__ __launch_bounds__(256) void k_mlp(
    const float* __restrict__ numc, const float* __restrict__ denc,
    const float* __restrict__ conv_b,
    const float* __restrict__ fw1, const float* __restrict__ fb1,
    const float* __restrict__ fw2, const float* __restrict__ fb2,
    const float* __restrict__ gw1, const float* __restrict__ gb1,
    const float* __restrict__ gw2, const float* __restrict__ gb2,
    float* __restrict__ tf, float* __restrict__ tg){
  const float* w1 = blockIdx.y ? gw1 : fw1;
  const float* b1 = blockIdx.y ? gb1 : fb1;
  const float* w2 = blockIdx.y ? gw2 : fw2;
  const float* b2 = blockIdx.y ? gb2 : fb2;
  float* out = blockIdx.y ? tg : tf;
  int t = threadIdx.x;
  int c = t & 127, kh = t >> 7;
  int o = t & 63, kh2 = t >> 6;
  int r0 = blockIdx.x*32;
  __shared__ float es[32][132];
  // ---- embed: l2norm(elu(numc/denc)) + conv_b ----
  { int row = t >> 3, c0 = (t & 7)*16;
    float inv = 1.f / denc[r0 + row];
    float ev[16]; float ss = 0.f;
#pragma unroll
    for (int k = 0; k < 4; k++){
      float4 v = *(const float4*)&numc[(size_t)(r0 + row)*D2 + c0 + 4*k];
      float e0 = eluf(v.x*inv), e1 = eluf(v.y*inv), e2 = eluf(v.z*inv), e3 = eluf(v.w*inv);
      ev[4*k]=e0; ev[4*k+1]=e1; ev[4*k+2]=e2; ev[4*k+3]=e3;
      ss += e0*e0 + e1*e1 + e2*e2 + e3*e3;
    }
    ss += __shfl_xor(ss, 1); ss += __shfl_xor(ss, 2); ss += __shfl_xor(ss, 4);
    float invn = 1.f / fmaxf(sqrtf(ss), 1e-12f);
#pragma unroll
    for (int k = 0; k < 16; k++) es[row][c0 + k] = ev[k]*invn + conv_b[c0 + k];
  }
  float rw1[64];
#pragma unroll
  for (int i = 0; i < 64; i++) rw1[i] = w1[(kh*64 + i)*128 + c];
  float rw2[32];
#pragma unroll
  for (int i = 0; i < 32; i++) rw2[i] = w2[(kh2*32 + i)*64 + o];
  float bb1 = b1[c], bb2 = b2[o];
  __shared__ float hidp[2][4][128];
  __shared__ float hid[4][128];
  __shared__ float outp[4][4][64];
  __syncthreads();
  for (int it = 0; it < 8; it++){
    int rb4 = it*4;
#pragma unroll
    for (int g = 0; g < 4; g++){
      float s = 0.f;
#pragma unroll
      for (int i = 0; i < 64; i++) s += es[rb4 + g][kh*64 + i]*rw1[i];
      hidp[kh][g][c] = s;
    }
    __syncthreads();
#pragma unroll
    for (int gg = 0; gg < 2; gg++){
      int g = kh + 2*gg;
      hid[g][c] = eluf(bb1 + hidp[0][g][c] + hidp[1][g][c]);
    }
    __syncthreads();
#pragma unroll
    for (int g = 0; g < 4; g++){
      float s = 0.f;
#pragma unroll
      for (int i = 0; i < 32; i++) s += hid[g][kh2*32 + i]*rw2[i];
      outp[kh2][g][o] = s;
    }
    __syncthreads();
    { int g = t >> 6;
      out[(size_t)(r0 + rb4 + g)*64 + o] =
        eluf(bb2 + outp[0][g][o] + outp[1][g][o] + outp[2][g][o] + outp[3][g][o]); }
    __syncthreads();
  }
}

// ---------------- E4: pred = rowwise dot of gathered tf/tg ----------------
__global__ __launch_bounds__(256) void k_pred(
    const int* __restrict__ ts, const float4* __restrict__ tf4,
    const float4* __restrict__ tg4, float* __restrict__ out){
  int p = blockIdx.x*16 + (threadIdx.x >> 4);
  int l = threadIdx.x & 15;
  int i = ts[2*p], j = ts[2*p + 1];
  float4 a = tf4[(size_t)i*16 + l], b = tg4[(size_t)j*16 + l];
  float v = a.x*b.x + a.y*b.y + a.z*b.z + a.w*b.w;
  v += __shfl_xor(v, 1); v += __shfl_xor(v, 2);
  v += __shfl_xor(v, 4); v += __shfl_xor(v, 8);
  if (l == 0) out[p] = v;
}

// ---------------- workspace layout ----------------
#define OFF_MASK  ((size_t)0)
#define OFF_X16   ((size_t)8388608)
#define OFF_WT16  ((size_t)20971520)
#define OFF_HT16  ((size_t)21757952)
#define OFF_WH1   ((size_t)30146560)
#define OFF_WH2   ((size_t)30212096)
#define OFF_GMAX  ((size_t)30277632)
#define OFF_C1    ((size_t)30277888)
#define OFF_C2    ((size_t)30343424)
#define OFF_NUM1  ((size_t)30408960)
#define OFF_DEN1  ((size_t)47186176)
#define OFF_GT16  ((size_t)47251712)
#define OFF_WC1L  ((size_t)49348864)
#define OFF_WC2L  ((size_t)49381632)
#define OFF_NUMC  ((size_t)49414400)
#define OFF_DENC  ((size_t)53608704)
#define OFF_TF    ((size_t)53641472)
#define OFF_TG    ((size_t)55738624)

extern "C" void kernel_launch(void* const* d_in, const int* in_sizes, int n_in,
                              void* d_out, int out_size, void* d_ws, size_t ws_size,
                              hipStream_t stream){
  const float* x      = (const float*)d_in[0];
  const int*   adj    = (const int*)d_in[1];
  const int*   ts     = (const int*)d_in[2];
  const float* head_W = (const float*)d_in[3];
  const float* head_a = (const float*)d_in[4];
  const float* head_b = (const float*)d_in[5];
  const float* conv_w = (const float*)d_in[6];
  const float* conv_cb= (const float*)d_in[7];
  const float* conv_a = (const float*)d_in[8];
  const float* conv_b = (const float*)d_in[9];
  const float* tf_w1  = (const float*)d_in[10];
  const float* tf_b1  = (const float*)d_in[11];
  const float* tf_w2  = (const float*)d_in[12];
  const float* tf_b2  = (const float*)d_in[13];
  const float* tg_w1  = (const float*)d_in[14];
  const float* tg_b1  = (const float*)d_in[15];
  const float* tg_w2  = (const float*)d_in[16];
  const float* tg_b2  = (const float*)d_in[17];
  float* outp = (float*)d_out;
  char* ws = (char*)d_ws;

  unsigned* maskw = (unsigned*)(ws + OFF_MASK);
  f16*   x16   = (f16*)(ws + OFF_X16);
  f16*   Wt16  = (f16*)(ws + OFF_WT16);
  f16*   hT16  = (f16*)(ws + OFF_HT16);
  float* wh1   = (float*)(ws + OFF_WH1);
  float* wh2   = (float*)(ws + OFF_WH2);
  unsigned* gmax = (unsigned*)(ws + OFF_GMAX);
  float* c1    = (float*)(ws + OFF_C1);
  float* c2    = (float*)(ws + OFF_C2);
  float* num1  = (float*)(ws + OFF_NUM1);
  float* den1  = (float*)(ws + OFF_DEN1);
  f16*   gT16  = (f16*)(ws + OFF_GT16);
  float* wc1L  = (float*)(ws + OFF_WC1L);
  float* wc2L  = (float*)(ws + OFF_WC2L);
  float* numc  = (float*)(ws + OFF_NUMC);
  float* denc  = (float*)(ws + OFF_DENC);
  float* tf    = (float*)(ws + OFF_TF);
  float* tg    = (float*)(ws + OFF_TG);

  // zero atomic accumulators (ws is poisoned before every call)
  hipMemsetAsync(wh1, 0, 131328, stream);                         // wh1+wh2+gmax
  hipMemsetAsync(num1, 0, 16842752, stream);                      // num1+den1
  hipMemsetAsync(numc, 0, 4227072, stream);                       // numc+denc

  k_prep   <<<72192, 256, 0, stream>>>((const int4*)adj, maskw, x, x16, head_W, Wt16);
  k_gemm_h <<<dim3(NN/64, DT/128), 256, 0, stream>>>(x16, Wt16, head_a, hT16, wh1, wh2);
  k_rowterms<<<64, 256, 0, stream>>>(wh2, c1, c2, gmax);
  k_agg_head<<<dim3(NN/64, 4, 2), 256, 0, stream>>>(hT16, maskw, wh1, c1, c2, gmax, num1, den1);
  k_merge_conv<<<NN/2, 256, 0, stream>>>(num1, den1, head_b, conv_w, conv_cb, conv_a, gT16, wc1L, wc2L);
  k_agg_conv<<<dim3(NN/64, 8), 256, 0, stream>>>(gT16, maskw, wc1L, wc2L, numc, denc);
  k_mlp    <<<dim3(NN/32, 2), 256, 0, stream>>>(numc, denc, conv_b,
                                                tf_w1, tf_b1, tf_w2, tf_b2,
                                                tg_w1, tg_b1, tg_w2, tg_b2, tf, tg);
  k_pred   <<<EPAIRS/16, 256, 0, stream>>>(ts, (const float4*)tf, (const float4*)tg, outp);
}